// Round 11
// baseline (1490.264 us; speedup 1.0000x reference)
//
#include <hip/hip_runtime.h>
#include <hip/hip_fp16.h>

// DNCClassifier: DNC memory machinery is dead code (inputs built with the
// initial zero read vector); output = LSTM-final-h @ W_fc.T + b_fc.
//   gates_t = x_t @ W_ih[:, :27].T + (b_ih + b_hh) + h @ W_hh.T
// Sizes: B=128, T=512, IN=27, H=256 (4H=1024), OUT=128.
//
// R11: R10 step = 3994 cyc, decomposed: L2 BW 2040 + ~750 exposed L2 latency
// (back-half stream batches had only ~64 cyc cover) + barriers. Fix by
// raising arithmetic intensity: 2 batch elements per block (64 blocks).
// Each weight quad (VGPR/LDS/L2) is dotted against TWO h-vectors:
//   VALU 2048 cyc/SIMD (issue floor), L2 1.97 MB/XCD -> 1090 cyc,
//   LDS 147 KB -> ~1500 cyc, latency cover per JHB block doubles.
// Step ~= VALU-bound 2400-2600 cyc; total = 512 x step (fewer fatter blocks
// win since batch parallelism, not CU count, is the limit).
//   wave w (0..7): half = w>>2 (K-half AND owned element), u=(w&3)*64+lane.
//   64 weight quads/thread, f = 4*jq + g (jq = h-quad 0..15, g = gate):
//     f 0..15 VGPR (64 regs) | f 16..33 LDS (147 KB) | f 34..63 streamed
//   h via wave-uniform broadcast ds_read_b128 (no readlane, no AGPR).

typedef _Float16 h2t __attribute__((ext_vector_type(2)));
typedef unsigned int u32x4 __attribute__((ext_vector_type(4)));

#if defined(__has_builtin)
#  if __has_builtin(__builtin_amdgcn_fdot2)
#    define HAVE_FDOT2 1
#  endif
#endif

__device__ __forceinline__ h2t bc2(unsigned int v) {
  union { unsigned int u; h2t h; } x; x.u = v; return x.h;
}
__device__ __forceinline__ unsigned int pk(float a, float b) {
  union { h2t h; unsigned int u; } x;
  x.h[0] = (_Float16)a; x.h[1] = (_Float16)b;
  return x.u;
}
__device__ __forceinline__ float fdot2f(h2t a, h2t b, float c) {
#ifdef HAVE_FDOT2
  return __builtin_amdgcn_fdot2(a, b, c, false);
#else
  return c + (float)a[0] * (float)b[0] + (float)a[1] * (float)b[1];
#endif
}
__device__ __forceinline__ float dot4(u32x4 w, u32x4 h, float a) {
  a = fdot2f(bc2(w[0]), bc2(h[0]), a);
  a = fdot2f(bc2(w[1]), bc2(h[1]), a);
  a = fdot2f(bc2(w[2]), bc2(h[2]), a);
  a = fdot2f(bc2(w[3]), bc2(h[3]), a);
  return a;
}
__device__ __forceinline__ float sigmf_(float x) {
  return 1.f / (1.f + __expf(-x));
}
__device__ __forceinline__ float tanhf_(float x) {
  float xc = fminf(15.f, fmaxf(-15.f, x));
  float e = __expf(2.f * xc);
  return (e - 1.f) / (e + 1.f);
}

// ---- workspace layout (bytes) ----
// P : [(t*128+b)*256+u] uint2 (gates i,f,g,o fp16, bias folded in) - 128 MB
// W : u32x4[f*512 + v], f = 0..63 - 512 KB, coalesced 16 B/lane per f-row
#define WS_P_OFF 0ull
#define WS_W_OFF 134217728ull
#define WS_NEED  134742016ull

__global__ void prep_w(const float* __restrict__ W_hh,
                       unsigned char* __restrict__ ws) {
  int j = blockIdx.x * 256 + threadIdx.x;  // dword id, 512 blocks -> j < 131072
  int e = j & 3, v = (j >> 2) & 511, f = j >> 11;
  int jq = f >> 2, g = f & 3;
  int w = v >> 6, l = v & 63;
  int half = w >> 2;
  int u = ((w & 3) << 6) + l;
  int k2 = 64 * half + 4 * jq + e;
  int r = g * 256 + u;
  ((unsigned int*)(ws + WS_W_OFF))[j] =
      pk(W_hh[r * 256 + 2 * k2], W_hh[r * 256 + 2 * k2 + 1]);
}

// P[t,b,u,:] = bias(u,:) + x[b,t,:27] @ W_ih[:, :27].T  (fp16x4 out)
__global__ __launch_bounds__(256) void prep_p(const float* __restrict__ x,
                                              const float* __restrict__ W_ih,
                                              const float* __restrict__ b_ih,
                                              const float* __restrict__ b_hh,
                                              unsigned char* __restrict__ ws) {
  __shared__ unsigned int sX[64][14];
  const int u = threadIdx.x;
  const int t = blockIdx.x >> 1;
  const int b0 = (blockIdx.x & 1) << 6;
  unsigned int wih[4][14];
  float bias[4];
#pragma unroll
  for (int g = 0; g < 4; ++g) {
    const float* row = W_ih + (size_t)(g * 256 + u) * 47;
    bias[g] = b_ih[g * 256 + u] + b_hh[g * 256 + u];
#pragma unroll
    for (int j = 0; j < 14; ++j) {
      float a = row[2 * j];
      float b = (2 * j + 1 < 27) ? row[2 * j + 1] : 0.f;
      wih[g][j] = pk(a, b);
    }
  }
#pragma unroll 1
  for (int j = u; j < 896; j += 256) {        // stage 64 rows of x
    int row = j / 14, c2 = j - 14 * row;
    const float* xr = x + ((size_t)(b0 + row) * 512 + t) * 27;
    float a = xr[2 * c2];
    float bb = (2 * c2 + 1 < 27) ? xr[2 * c2 + 1] : 0.f;
    sX[row][c2] = pk(a, bb);
  }
  __syncthreads();
  uint2* Pout = (uint2*)(ws + WS_P_OFF);
#pragma unroll 2
  for (int p = 0; p < 64; ++p) {
    float a0 = bias[0], a1 = bias[1], a2 = bias[2], a3 = bias[3];
#pragma unroll
    for (int j = 0; j < 14; ++j) {
      h2t xx = bc2(sX[p][j]);
      a0 = fdot2f(bc2(wih[0][j]), xx, a0);
      a1 = fdot2f(bc2(wih[1][j]), xx, a1);
      a2 = fdot2f(bc2(wih[2][j]), xx, a2);
      a3 = fdot2f(bc2(wih[3][j]), xx, a3);
    }
    uint2 o; o.x = pk(a0, a1); o.y = pk(a2, a3);
    Pout[((size_t)t * 128 + (b0 + p)) * 256 + u] = o;
  }
}

// one jq-block for 2 elements: 2 broadcast h reads + 8 dots per weight set
#define JH2(jq, W0, W1, W2, W3)          \
  {                                      \
    u32x4 hM = rdM[jq], hO = rdO[jq];    \
    aM0 = dot4(W0, hM, aM0);             \
    aO0 = dot4(W0, hO, aO0);             \
    aM1 = dot4(W1, hM, aM1);             \
    aO1 = dot4(W1, hO, aO1);             \
    aM2 = dot4(W2, hM, aM2);             \
    aO2 = dot4(W2, hO, aO2);             \
    aM3 = dot4(W3, hM, aM3);             \
    aO3 = dot4(W3, hO, aO3);             \
  }

// Persistent LSTM scan. grid=64 (TWO batch elements per block), 512 threads.
__global__ __launch_bounds__(512) void scan_k(
    const unsigned char* __restrict__ ws, const float* __restrict__ W_fc,
    const float* __restrict__ b_fc, float* __restrict__ out) {
  __shared__ u32x4 sW[18 * 512];               // 147,456 B LDS weight tier
  __shared__ u32x4 sH[2][2][32];               // [elem][buf][quad] h dbuf
  __shared__ float4 sRed[2][256];              // [elem] cross-half partials
  __shared__ float sHF[2][256];                // final h per elem for head
  const int v = threadIdx.x, b0 = blockIdx.x * 2;
  const int w = v >> 6, l = v & 63;
  const int half = w >> 2;                     // K-half AND owned element
  const int u = ((w & 3) << 6) + l;
  const int me = half, ot = half ^ 1;
  const u32x4* Wq = (const u32x4*)(ws + WS_W_OFF);

  // tier 1: VGPR weights (16 quads = 64 regs)
  u32x4 wr[16];
#pragma unroll
  for (int f = 0; f < 16; ++f) wr[f] = Wq[f * 512 + v];
  // tier 2: LDS weights (18 quads = 147 KB)
#pragma unroll
  for (int f = 0; f < 18; ++f) sW[f * 512 + v] = Wq[(16 + f) * 512 + v];
  if (v < 128) ((u32x4*)sH)[v] = u32x4{0u, 0u, 0u, 0u};  // all h bufs = 0

  const uint2* Pbuf = (const uint2*)(ws + WS_P_OFF);
  uint2 pP = Pbuf[((size_t)0 * 128 + (b0 + me)) * 256 + u];
  float c = 0.f, hval = 0.f;
  __syncthreads();

#pragma unroll 1
  for (int t = 0; t < 512; ++t) {
    // tier-3 stream: 8 quads in flight, first batch has 8 JH2 blocks of cover
    u32x4 t0 = Wq[34 * 512 + v], t1 = Wq[35 * 512 + v];
    u32x4 t2 = Wq[36 * 512 + v], t3 = Wq[37 * 512 + v];
    u32x4 t4 = Wq[38 * 512 + v], t5 = Wq[39 * 512 + v];
    u32x4 t6 = Wq[40 * 512 + v], t7 = Wq[41 * 512 + v];

    const u32x4* rdM = &sH[me][t & 1][half << 4];  // broadcast (uniform addr)
    const u32x4* rdO = &sH[ot][t & 1][half << 4];
    float aM0 = 0.f, aM1 = 0.f, aM2 = 0.f, aM3 = 0.f;
    float aO0 = 0.f, aO1 = 0.f, aO2 = 0.f, aO3 = 0.f;
    JH2(0, wr[0], wr[1], wr[2], wr[3]);
    JH2(1, wr[4], wr[5], wr[6], wr[7]);
    JH2(2, wr[8], wr[9], wr[10], wr[11]);
    JH2(3, wr[12], wr[13], wr[14], wr[15]);
    JH2(4, sW[0 * 512 + v], sW[1 * 512 + v], sW[2 * 512 + v], sW[3 * 512 + v]);
    JH2(5, sW[4 * 512 + v], sW[5 * 512 + v], sW[6 * 512 + v], sW[7 * 512 + v]);
    JH2(6, sW[8 * 512 + v], sW[9 * 512 + v], sW[10 * 512 + v], sW[11 * 512 + v]);
    JH2(7, sW[12 * 512 + v], sW[13 * 512 + v], sW[14 * 512 + v], sW[15 * 512 + v]);
    JH2(8, sW[16 * 512 + v], sW[17 * 512 + v], t0, t1);   // f32,33 LDS; 34,35
    t0 = Wq[42 * 512 + v]; t1 = Wq[43 * 512 + v];
    JH2(9, t2, t3, t4, t5);                               // f36..39
    t2 = Wq[44 * 512 + v]; t3 = Wq[45 * 512 + v];
    t4 = Wq[46 * 512 + v]; t5 = Wq[47 * 512 + v];
    JH2(10, t6, t7, t0, t1);                              // f40..43
    t6 = Wq[48 * 512 + v]; t7 = Wq[49 * 512 + v];
    t0 = Wq[50 * 512 + v]; t1 = Wq[51 * 512 + v];
    JH2(11, t2, t3, t4, t5);                              // f44..47
    t2 = Wq[52 * 512 + v]; t3 = Wq[53 * 512 + v];
    t4 = Wq[54 * 512 + v]; t5 = Wq[55 * 512 + v];
    JH2(12, t6, t7, t0, t1);                              // f48..51
    t6 = Wq[56 * 512 + v]; t7 = Wq[57 * 512 + v];
    t0 = Wq[58 * 512 + v]; t1 = Wq[59 * 512 + v];
    JH2(13, t2, t3, t4, t5);                              // f52..55
    t2 = Wq[60 * 512 + v]; t3 = Wq[61 * 512 + v];
    t4 = Wq[62 * 512 + v]; t5 = Wq[63 * 512 + v];
    JH2(14, t6, t7, t0, t1);                              // f56..59
    JH2(15, t2, t3, t4, t5);                              // f60..63

    sRed[ot][u] = make_float4(aO0, aO1, aO2, aO3);  // give other-elem partials
    __syncthreads();                           // partials visible; h reads done

    {  // pointwise update of the OWNED element (all 512 threads, no idle)
      float4 o = sRed[me][u];
      h2t p01 = bc2(pP.x), p23 = bc2(pP.y);
      float gi = aM0 + o.x + (float)p01[0];
      float gf = aM1 + o.y + (float)p01[1];
      float gg = aM2 + o.z + (float)p23[0];
      float go = aM3 + o.w + (float)p23[1];
      c = sigmf_(gf) * c + sigmf_(gi) * tanhf_(gg);
      hval = sigmf_(go) * tanhf_(c);
      ((_Float16*)(&sH[me][(t + 1) & 1][0]))[u] = (_Float16)hval;
      if (t == 511) sHF[me][u] = hval;
      int tn = (t < 511) ? t + 1 : 511;
      pP = Pbuf[((size_t)tn * 128 + (b0 + me)) * 256 + u];
    }
    __syncthreads();                           // h_{t+1} visible; sRed reusable
  }

  // --- classifier head on final h, both elements (sHF covered by barrier) ---
  if (v < 256) {
    const int elem = v >> 7, row = v & 127;
    const float4* wrow = (const float4*)(W_fc + (size_t)row * 256);
    float a = b_fc[row];
#pragma unroll 8
    for (int q = 0; q < 64; ++q) {
      float4 wv = wrow[q];
      float4 hh = ((const float4*)&sHF[elem][0])[q];
      a += wv.x * hh.x + wv.y * hh.y + wv.z * hh.z + wv.w * hh.w;
    }
    out[(size_t)(b0 + elem) * 128 + row] = a;
  }
}

extern "C" void kernel_launch(void* const* d_in, const int* in_sizes, int n_in,
                              void* d_out, int out_size, void* d_ws,
                              size_t ws_size, hipStream_t stream) {
  const float* x    = (const float*)d_in[0];
  // d_in[1] = input_lengths: unused by the reference
  const float* W_ih = (const float*)d_in[2];
  const float* W_hh = (const float*)d_in[3];
  const float* b_ih = (const float*)d_in[4];
  const float* b_hh = (const float*)d_in[5];
  // d_in[6] = W_xi, d_in[7] = b_xi: dead code in the reference
  const float* W_fc = (const float*)d_in[8];
  const float* b_fc = (const float*)d_in[9];
  unsigned char* ws = (unsigned char*)d_ws;

  if (ws_size < WS_NEED) return;  // signature: output stays poisoned

  prep_w<<<512, 256, 0, stream>>>(W_hh, ws);
  prep_p<<<1024, 256, 0, stream>>>(x, W_ih, b_ih, b_hh, ws);
  scan_k<<<64, 512, 0, stream>>>(ws, W_fc, b_fc, (float*)d_out);
}